// Round 8
// baseline (304.598 us; speedup 1.0000x reference)
//
#include <hip/hip_runtime.h>
#include <math.h>

#define EPS 1e-5f
#define ROWS 4096  // B*N

typedef __attribute__((ext_vector_type(8))) short short8;
typedef __attribute__((ext_vector_type(4))) float floatx4;

__device__ inline short f2bf(float f) {
    unsigned u = __builtin_bit_cast(unsigned, f);
    unsigned r = (u + 0x7fffu + ((u >> 16) & 1u)) >> 16;
    return (short)r;
}
__device__ inline float bf2f(short s) {
    unsigned u = ((unsigned)(unsigned short)s) << 16;
    return __builtin_bit_cast(float, u);
}

// ---------------------------------------------------------------------------
// prep: fused weight->bf16 conversion (blocks 0..1279), LN(q/k/v)->bf16
// (blocks 1280..4351), and zeroing of qgl/kgl (block 4352). 256 threads.
// ---------------------------------------------------------------------------
__global__ __launch_bounds__(256) void prep(
    const float* __restrict__ Win, const float* __restrict__ Wout,
    const float* __restrict__ Wup, const float* __restrict__ Wdn,
    short* __restrict__ Winbf, short* __restrict__ Woutbf,
    short* __restrict__ Wupbf, short* __restrict__ Wdnbf,
    const float* __restrict__ q, const float* __restrict__ k,
    const float* __restrict__ v, const float* __restrict__ g,
    const float* __restrict__ bb, short* __restrict__ qkvln,
    float* __restrict__ zbase) {
    int bid = blockIdx.x;
    int t = threadIdx.x;
    if (bid < 1280) {  // weight convert, 2048 elems per block
        int lb = bid;
        const float* src;
        short* dst;
        if (lb < 128) { src = Win; dst = Winbf; }
        else if (lb < 256) { lb -= 128; src = Wout; dst = Woutbf; }
        else if (lb < 768) { lb -= 256; src = Wup; dst = Wupbf; }
        else { lb -= 768; src = Wdn; dst = Wdnbf; }
        int idx = (lb * 256 + t) * 8;
        float4 v0 = *(const float4*)(src + idx);
        float4 v1 = *(const float4*)(src + idx + 4);
        short8 o;
        o[0] = f2bf(v0.x); o[1] = f2bf(v0.y); o[2] = f2bf(v0.z); o[3] = f2bf(v0.w);
        o[4] = f2bf(v1.x); o[5] = f2bf(v1.y); o[6] = f2bf(v1.z); o[7] = f2bf(v1.w);
        *(short8*)(dst + idx) = o;
    } else if (bid < 4352) {  // layernorm + bf16, 4 rows per block
        int lb = bid - 1280;
        int tensor = lb >> 10;
        const float* x = tensor == 0 ? q : (tensor == 1 ? k : v);
        int row = (lb & 1023) * 4 + (t >> 6);
        int col = (t & 63) * 8;
        const float* xr = x + (size_t)row * 512 + col;
        float4 v0 = *(const float4*)xr;
        float4 v1 = *(const float4*)(xr + 4);
        float s = v0.x + v0.y + v0.z + v0.w + v1.x + v1.y + v1.z + v1.w;
        float sq = v0.x * v0.x + v0.y * v0.y + v0.z * v0.z + v0.w * v0.w +
                   v1.x * v1.x + v1.y * v1.y + v1.z * v1.z + v1.w * v1.w;
#pragma unroll
        for (int off = 32; off; off >>= 1) {
            s += __shfl_xor(s, off);
            sq += __shfl_xor(sq, off);
        }
        float m = s * (1.f / 512.f);
        float rstd = rsqrtf(sq * (1.f / 512.f) - m * m + EPS);
        float4 g0 = *(const float4*)(g + col);
        float4 g1 = *(const float4*)(g + col + 4);
        float4 b0 = *(const float4*)(bb + col);
        float4 b1 = *(const float4*)(bb + col + 4);
        short8 o;
        o[0] = f2bf((v0.x - m) * rstd * g0.x + b0.x);
        o[1] = f2bf((v0.y - m) * rstd * g0.y + b0.y);
        o[2] = f2bf((v0.z - m) * rstd * g0.z + b0.z);
        o[3] = f2bf((v0.w - m) * rstd * g0.w + b0.w);
        o[4] = f2bf((v1.x - m) * rstd * g1.x + b1.x);
        o[5] = f2bf((v1.y - m) * rstd * g1.y + b1.y);
        o[6] = f2bf((v1.z - m) * rstd * g1.z + b1.z);
        o[7] = f2bf((v1.w - m) * rstd * g1.w + b1.w);
        *(short8*)(qkvln + (size_t)(tensor * 4096 + row) * 512 + col) = o;
    } else {  // zero qgl/kgl (1024 floats)
        float4 z = {0.f, 0.f, 0.f, 0.f};
        *(float4*)(zbase + t * 4) = z;
    }
}

// Single-tensor LN + bf16 (for x2 = LN(q2)). grid 1024 x 256 thr.
__global__ __launch_bounds__(256) void lnsingle(
    const float* __restrict__ x, const float* __restrict__ g,
    const float* __restrict__ bb, short* __restrict__ out) {
    int t = threadIdx.x;
    int row = blockIdx.x * 4 + (t >> 6);
    int col = (t & 63) * 8;
    const float* xr = x + (size_t)row * 512 + col;
    float4 v0 = *(const float4*)xr;
    float4 v1 = *(const float4*)(xr + 4);
    float s = v0.x + v0.y + v0.z + v0.w + v1.x + v1.y + v1.z + v1.w;
    float sq = v0.x * v0.x + v0.y * v0.y + v0.z * v0.z + v0.w * v0.w +
               v1.x * v1.x + v1.y * v1.y + v1.z * v1.z + v1.w * v1.w;
#pragma unroll
    for (int off = 32; off; off >>= 1) {
        s += __shfl_xor(s, off);
        sq += __shfl_xor(sq, off);
    }
    float m = s * (1.f / 512.f);
    float rstd = rsqrtf(sq * (1.f / 512.f) - m * m + EPS);
    float4 g0 = *(const float4*)(g + col);
    float4 g1 = *(const float4*)(g + col + 4);
    float4 b0 = *(const float4*)(bb + col);
    float4 b1 = *(const float4*)(bb + col + 4);
    short8 o;
    o[0] = f2bf((v0.x - m) * rstd * g0.x + b0.x);
    o[1] = f2bf((v0.y - m) * rstd * g0.y + b0.y);
    o[2] = f2bf((v0.z - m) * rstd * g0.z + b0.z);
    o[3] = f2bf((v0.w - m) * rstd * g0.w + b0.w);
    o[4] = f2bf((v1.x - m) * rstd * g1.x + b1.x);
    o[5] = f2bf((v1.y - m) * rstd * g1.y + b1.y);
    o[6] = f2bf((v1.z - m) * rstd * g1.z + b1.z);
    o[7] = f2bf((v1.w - m) * rstd * g1.w + b1.w);
    *(short8*)(out + (size_t)row * 512 + col) = o;
}

// ---------------------------------------------------------------------------
// bf16 MFMA NT GEMM, BK=64 (two 32-K sub-tiles per barrier pair).
// Tile TM x TN, 2x2 waves, 16x16x32 MFMA, global_load_lds width-16 staging.
// EPI: 0 plain, 2 +bias+resid, 3 gelu(x+bias).  OUT_BF16 selects C dtype.
// ---------------------------------------------------------------------------
template <int TM, int TN, int EPI, bool OUT_BF16>
__global__ __launch_bounds__(256) void mfma_gemm_nt(
    const short* __restrict__ A, const short* __restrict__ B,
    void* __restrict__ C, int M, int N, int K,
    const float* __restrict__ bias, const float* __restrict__ resid) {
    constexpr int FI = TM / 32;
    constexpr int FJ = TN / 32;
    __shared__ short As[2 * TM * 32];
    __shared__ short Bs[2 * TN * 32];
    int t = threadIdx.x;
    int m0 = blockIdx.y * TM, n0 = blockIdx.x * TN;
    int w = t >> 6, lane = t & 63;
    int wm = (w & 1) * (TM / 2), wn = (w >> 1) * (TN / 2);
    floatx4 acc[FI][FJ];
#pragma unroll
    for (int i = 0; i < FI; ++i)
#pragma unroll
        for (int j = 0; j < FJ; ++j) acc[i][j] = (floatx4){0.f, 0.f, 0.f, 0.f};

    int arow = t >> 2, acol = (t & 3) * 8;
    const short* Ag = A + (size_t)(m0 + arow) * K + acol;
    const short* Bg = B + (size_t)(n0 + arow) * K + acol;
    int ldsbase = w * 1024;  // bytes, wave-uniform

    for (int k0 = 0; k0 < K; k0 += 64) {
        __syncthreads();
#pragma unroll
        for (int u = 0; u < 2; ++u) {
#pragma unroll
            for (int r = 0; r < TM / 64; ++r)
                __builtin_amdgcn_global_load_lds(
                    (const __attribute__((address_space(1))) void*)(Ag + (size_t)r * 64 * K + k0 + 32 * u),
                    (__attribute__((address_space(3))) void*)((char*)As + u * TM * 64 + r * 4096 + ldsbase),
                    16, 0, 0);
#pragma unroll
            for (int r = 0; r < TN / 64; ++r)
                __builtin_amdgcn_global_load_lds(
                    (const __attribute__((address_space(1))) void*)(Bg + (size_t)r * 64 * K + k0 + 32 * u),
                    (__attribute__((address_space(3))) void*)((char*)Bs + u * TN * 64 + r * 4096 + ldsbase),
                    16, 0, 0);
        }
        __syncthreads();
        int krow = (lane >> 4) * 8;
#pragma unroll
        for (int u = 0; u < 2; ++u) {
            short8 af[FI], bf[FJ];
#pragma unroll
            for (int i = 0; i < FI; ++i)
                af[i] = *(const short8*)&As[u * TM * 32 + (wm + i * 16 + (lane & 15)) * 32 + krow];
#pragma unroll
            for (int j = 0; j < FJ; ++j)
                bf[j] = *(const short8*)&Bs[u * TN * 32 + (wn + j * 16 + (lane & 15)) * 32 + krow];
#pragma unroll
            for (int i = 0; i < FI; ++i)
#pragma unroll
                for (int j = 0; j < FJ; ++j)
                    acc[i][j] = __builtin_amdgcn_mfma_f32_16x16x32_bf16(
                        af[i], bf[j], acc[i][j], 0, 0, 0);
        }
    }

    int col = lane & 15, rbase = (lane >> 4) * 4;
#pragma unroll
    for (int i = 0; i < FI; ++i) {
#pragma unroll
        for (int j = 0; j < FJ; ++j) {
            int gcol = n0 + wn + j * 16 + col;
#pragma unroll
            for (int r = 0; r < 4; ++r) {
                int grow = m0 + wm + i * 16 + rbase + r;
                float v = acc[i][j][r];
                if (EPI == 2) v += bias[gcol] + resid[(size_t)grow * N + gcol];
                if (EPI == 3) {
                    v += bias[gcol];
                    v = 0.5f * v * (1.f + erff(v * 0.70710678118654752f));
                }
                if (OUT_BF16)
                    ((short*)C)[(size_t)grow * N + gcol] = f2bf(v);
                else
                    ((float*)C)[(size_t)grow * N + gcol] = v;
            }
        }
    }
}

// ---------------------------------------------------------------------------
// Per (head,row) stats from bf16 fqkv: mean, 1/norm, var(ddof=1).
// grid (4096, 2) y: fq/fk. 512 threads.
// ---------------------------------------------------------------------------
__global__ void head_stats2(const short* __restrict__ fqkv, float* __restrict__ S) {
    int row = blockIdx.x;
    int y = blockIdx.y;
    const short* f = fqkv + (size_t)y * 4096 * 512;
    float* base = S + (size_t)y * 98304;
    int t = threadIdx.x;
    int h = t >> 6, lane = t & 63;
    float v = bf2f(f[(size_t)row * 512 + t]);
    float s = v, sq = v * v;
#pragma unroll
    for (int off = 32; off; off >>= 1) {
        s += __shfl_xor(s, off);
        sq += __shfl_xor(sq, off);
    }
    if (lane == 0) {
        float m = s * (1.f / 64.f);
        int idx = h * ROWS + row;
        base[idx] = m;
        base[32768 + idx] = rsqrtf(sq);
        base[65536 + idx] = (sq - 64.f * m * m) * (1.f / 63.f);
    }
}

// Column means of LN(q)/LN(k) bf16 over 4096 rows. grid (128, 2), 512 thr.
__global__ void colmean_ln(const short* __restrict__ qkvln,
                           float* __restrict__ qgl, float* __restrict__ kgl) {
    int y = blockIdx.y;
    const short* f = qkvln + (size_t)y * 4096 * 512;
    float* o = y ? kgl : qgl;
    int col = threadIdx.x;
    int r0 = blockIdx.x * 32;
    float s = 0.f;
    for (int r = 0; r < 32; ++r) s += bf2f(f[(size_t)(r0 + r) * 512 + col]);
    atomicAdd(&o[col], s * (1.f / 4096.f));
}

// ---------------------------------------------------------------------------
// Fused: qg = qgl @ Win^T, kg = kgl @ Win^T (512-GEMV each), then per-head
// policy MLP -> wmix. One block, 512 threads.
// ---------------------------------------------------------------------------
__global__ __launch_bounds__(512) void policy_fused(
    const float* __restrict__ qgl, const float* __restrict__ kgl,
    const short* __restrict__ Winbf,
    const float* __restrict__ W1, const float* __restrict__ b1,
    const float* __restrict__ g, const float* __restrict__ bb,
    const float* __restrict__ W2, const float* __restrict__ b2,
    float* __restrict__ wmix) {
    __shared__ float qgl_s[512], kgl_s[512], qg_s[512], kg_s[512];
    int t = threadIdx.x;
    qgl_s[t] = qgl[t];
    kgl_s[t] = kgl[t];
    __syncthreads();
    const short* wr = Winbf + (size_t)t * 512;
    float accq = 0.f, acck = 0.f;
    for (int i = 0; i < 512; i += 8) {
        short8 w8 = *(const short8*)(wr + i);
#pragma unroll
        for (int u = 0; u < 8; ++u) {
            float wv = bf2f(w8[u]);
            accq += qgl_s[i + u] * wv;
            acck += kgl_s[i + u] * wv;
        }
    }
    qg_s[t] = accq;
    kg_s[t] = acck;
    __syncthreads();
    int h = t >> 6, j = t & 63;
    float acc = 0.f;
    const float* w1r = W1 + j * 128;
    for (int i = 0; i < 64; ++i) acc += qg_s[h * 64 + i] * w1r[i];
    for (int i = 0; i < 64; ++i) acc += kg_s[h * 64 + i] * w1r[64 + i];
    acc += b1[j];
    float s = acc, sq = acc * acc;
#pragma unroll
    for (int off = 32; off; off >>= 1) {
        s += __shfl_xor(s, off);
        sq += __shfl_xor(sq, off);
    }
    float m = s * (1.f / 64.f);
    float var = sq * (1.f / 64.f) - m * m;
    float xh = (acc - m) * rsqrtf(var + EPS) * g[j] + bb[j];
    float r = fmaxf(xh, 0.f);
    float l[3];
#pragma unroll
    for (int c = 0; c < 3; ++c) {
        float p = r * W2[c * 64 + j];
#pragma unroll
        for (int off = 32; off; off >>= 1) p += __shfl_xor(p, off);
        l[c] = p + b2[c];
    }
    if (j == 0) {
        float mx = fmaxf(l[0], fmaxf(l[1], l[2]));
        float e0 = expf(l[0] - mx), e1 = expf(l[1] - mx), e2 = expf(l[2] - mx);
        float inv = 1.f / (e0 + e1 + e2);
        wmix[h * 3 + 0] = e0 * inv;
        wmix[h * 3 + 1] = e1 * inv;
        wmix[h * 3 + 2] = e2 * inv;
    }
}

// ---------------------------------------------------------------------------
// K-side reduction, output-split: grid (4 dslices, 32 hb), 256 threads.
// Block (ds,hb) computes rows d0..d0+15 of M1=(K*rnk)^T V and M2=K^T V over
// ALL 1024 m-rows, writing directly to Mbuf (no partials, no reduce pass).
// ds==0 blocks also compute skv/smk. 8 acc VGPRs/thread.
// ---------------------------------------------------------------------------
__global__ __launch_bounds__(256) void kside2(
    const short* __restrict__ fqkv,
    const float* __restrict__ rnk, const float* __restrict__ kvv,
    const float* __restrict__ mk, float* __restrict__ Mbuf) {
    const short* fk = fqkv + (size_t)4096 * 512;
    const short* fv = fqkv + (size_t)2 * 4096 * 512;
    int ds = blockIdx.x, hb = blockIdx.y;
    int h = hb >> 2, b = hb & 3;
    int d0 = ds * 16;
    __shared__ float fvt[128 * 64];  // 32 KB
    __shared__ float fkt[128 * 16];  // 8 KB
    __shared__ float rs[128], kvs[128], mks[128];
    int t = threadIdx.x;
    int d = t >> 4, e0 = (t & 15) * 4;
    float m1a[4] = {}, m2a[4] = {};
    float skv = 0.f, smk = 0.f;
    for (int m0 = 0; m0 < 1024; m0 += 128) {
        __syncthreads();
        // stage fv tile (128 x 64)
#pragma unroll
        for (int u = 0; u < 4; ++u) {
            int row = u * 32 + (t >> 3), col = (t & 7) * 8;
            short8 vs = *(const short8*)&fv[(size_t)(b * 1024 + m0 + row) * 512 + h * 64 + col];
            int idx = row * 64 + col;
#pragma unroll
            for (int uu = 0; uu < 8; ++uu) fvt[idx + uu] = bf2f(vs[uu]);
        }
        // stage fk tile (128 x 16), cols d0..d0+15
        {
            int row = t >> 1, col = (t & 1) * 8;
            short8 ksx = *(const short8*)&fk[(size_t)(b * 1024 + m0 + row) * 512 + h * 64 + d0 + col];
            int idx = row * 16 + col;
#pragma unroll
            for (int uu = 0; uu < 8; ++uu) fkt[idx + uu] = bf2f(ksx[uu]);
        }
        if (t < 128) {
            int sidx = h * ROWS + b * 1024 + m0 + t;
            rs[t] = rnk[sidx];
            kvs[t] = kvv[sidx];
            mks[t] = mk[sidx];
        }
        __syncthreads();
#pragma unroll 4
        for (int mi = 0; mi < 128; ++mi) {
            float kd = fkt[mi * 16 + d];
            float kr = kd * rs[mi];
            float4 ve = *(const float4*)&fvt[mi * 64 + e0];
            m2a[0] += kd * ve.x; m2a[1] += kd * ve.y;
            m2a[2] += kd * ve.z; m2a[3] += kd * ve.w;
            m1a[0] += kr * ve.x; m1a[1] += kr * ve.y;
            m1a[2] += kr * ve.z; m1a[3] += kr * ve.w;
        }
        if (ds == 0 && t < 64) {
#pragma unroll 4
            for (int mi = 0; mi < 128; ++mi) {
                float fvv = fvt[mi * 64 + t];
                skv += kvs[mi] * fvv;
                smk += mks[mi] * fvv;
            }
        }
    }
    float* base = Mbuf + (size_t)hb * 8320;
    *(float4*)&base[(d0 + d) * 64 + e0] = (float4){m1a[0], m1a[1], m1a[2], m1a[3]};
    *(float4*)&base[4096 + (d0 + d) * 64 + e0] = (float4){m2a[0], m2a[1], m2a[2], m2a[3]};
    if (ds == 0 && t < 64) {
        base[8192 + t] = skv;
        base[8256 + t] = smk;
    }
}

// ---------------------------------------------------------------------------
// Q-side apply, 64 rows per block. grid (16, 32). Reads bf16 fq, writes bf16.
// ---------------------------------------------------------------------------
__global__ __launch_bounds__(256) void qside(
    const short* __restrict__ fqkv, const float* __restrict__ Mbuf,
    const float* __restrict__ rnq, const float* __restrict__ mq,
    const float* __restrict__ qv, const float* __restrict__ wmix,
    short* __restrict__ attn_out) {
    const short* fq = fqkv;
    int ntile = blockIdx.x, hb = blockIdx.y;
    int h = hb >> 2, b = hb & 3;
    __shared__ float M1s[4096], M2s[4096], fqt[4096];
    __shared__ float Skvs[64], Smks[64], rnqs[64], mqs[64], qvs[64];
    int t = threadIdx.x;
    const float* base = Mbuf + (size_t)hb * 8320;
#pragma unroll
    for (int u = 0; u < 4; ++u) {
        int idx = t * 4 + u * 1024;
        *(float4*)&M1s[idx] = *(const float4*)&base[idx];
        *(float4*)&M2s[idx] = *(const float4*)&base[4096 + idx];
    }
    int n0 = ntile * 64;
#pragma unroll
    for (int u = 0; u < 2; ++u) {
        int idx = u * 2048 + t * 8;
        int r = idx >> 6, d = idx & 63;
        short8 qs = *(const short8*)&fq[(size_t)(b * 1024 + n0 + r) * 512 + h * 64 + d];
#pragma unroll
        for (int uu = 0; uu < 8; ++uu) fqt[idx + uu] = bf2f(qs[uu]);
    }
    if (t < 64) {
        Skvs[t] = base[8192 + t];
        Smks[t] = base[8256 + t];
        int sidx = h * ROWS + b * 1024 + n0 + t;
        rnqs[t] = rnq[sidx];
        mqs[t] = mq[sidx];
        qvs[t] = qv[sidx];
    }
    __syncthreads();
    float cw = wmix[h * 3 + 0], covw = wmix[h * 3 + 1], vw = wmix[h * 3 + 2];
    int e = t & 63, rq = t >> 6;
    float a1[16] = {}, a2[16] = {};
    for (int d4 = 0; d4 < 64; d4 += 4) {
        float md1[4], md2[4];
#pragma unroll
        for (int dd = 0; dd < 4; ++dd) {
            md1[dd] = M1s[(d4 + dd) * 64 + e];
            md2[dd] = M2s[(d4 + dd) * 64 + e];
        }
#pragma unroll
        for (int i = 0; i < 16; ++i) {
            float4 f = *(const float4*)&fqt[(rq * 16 + i) * 64 + d4];
            a1[i] += f.x * md1[0] + f.y * md1[1] + f.z * md1[2] + f.w * md1[3];
            a2[i] += f.x * md2[0] + f.y * md2[1] + f.z * md2[2] + f.w * md2[3];
        }
    }
    float c2 = covw * (1.f / 64.f), c3 = vw * (1.f / 64.f);
#pragma unroll
    for (int i = 0; i < 16; ++i) {
        int rr = rq * 16 + i;
        float v = cw * rnqs[rr] * a1[i] + c2 * a2[i] + c3 * qvs[rr] * Skvs[e] -
                  covw * mqs[rr] * Smks[e];
        attn_out[(size_t)(b * 1024 + n0 + rr) * 512 + h * 64 + e] = f2bf(v);
    }
}

// ---------------------------------------------------------------------------
extern "C" void kernel_launch(void* const* d_in, const int* in_sizes, int n_in,
                              void* d_out, int out_size, void* d_ws, size_t ws_size,
                              hipStream_t stream) {
    const float* q = (const float*)d_in[0];
    const float* k = (const float*)d_in[1];
    const float* v = (const float*)d_in[2];
    const float* Win = (const float*)d_in[3];
    const float* Wout = (const float*)d_in[4];
    const float* bout = (const float*)d_in[5];
    const float* g1 = (const float*)d_in[6];
    const float* b1n = (const float*)d_in[7];
    const float* g2 = (const float*)d_in[8];
    const float* b2n = (const float*)d_in[9];
    const float* Wup = (const float*)d_in[10];
    const float* bup = (const float*)d_in[11];
    const float* Wdn = (const float*)d_in[12];
    const float* bdn = (const float*)d_in[13];
    const float* wpW1 = (const float*)d_in[14];
    const float* wpb1 = (const float*)d_in[15];
    const float* wpg = (const float*)d_in[16];
    const float* wpb = (const float*)d_in[17];
    const float* wpW2 = (const float*)d_in[18];
    const float* wpb2 = (const float*)d_in[19];
    float* out = (float*)d_out;

    float* wsf = (float*)d_ws;
    short* fqkv = (short*)wsf;                   // 12288x512 bf16
    short* qkvln = (short*)(wsf + 4000000);      // 12288x512 bf16
    short* attnbf = (short*)(wsf + 8000000);     // 4096x512 bf16
    short* x2bf = (short*)(wsf + 10000000);      // 4096x512 bf16
    short* hmid = (short*)(wsf + 12000000);      // 4096x2048 bf16
    short* Winbf = (short*)(wsf + 17000000);
    short* Woutbf = Winbf + 262144;
    short* Wupbf = Woutbf + 262144;
    short* Wdnbf = Wupbf + 1048576;
    float* S = wsf + 19000000;                   // [2][3][32768]
    float* qgl = S + 196608;                     // 512
    float* kgl = qgl + 512;                      // 512
    float* wmix = kgl + 512;                     // 32
    float* Mbuf = wsf + 19400000;                // 32*8320
    float* mqS = S, *rnqS = S + 32768, *qvS = S + 65536;
    float* mkS = S + 98304, *rnkS = S + 131072, *kvS = S + 163840;

    // 1. prep: weights->bf16, LN(q/k/v)->bf16, zero qgl/kgl
    prep<<<4353, 256, 0, stream>>>(Win, Wout, Wup, Wdn, Winbf, Woutbf, Wupbf,
                                   Wdnbf, q, k, v, g1, b1n, qkvln, qgl);

    // 2. stacked projection: fqkv = LN(qkv) @ Win^T  (M=12288), bf16 out
    mfma_gemm_nt<64, 128, 0, true><<<dim3(4, 192), 256, 0, stream>>>(
        qkvln, Winbf, fqkv, 12288, 512, 512, nullptr, nullptr);

    // 3. policy path: colmean of LN(q)/LN(k) -> GEMV + MLP -> wmix
    colmean_ln<<<dim3(128, 2), 512, 0, stream>>>(qkvln, qgl, kgl);
    policy_fused<<<1, 512, 0, stream>>>(qgl, kgl, Winbf, wpW1, wpb1, wpg, wpb,
                                        wpW2, wpb2, wmix);

    // 4. per-(head,row) stats
    head_stats2<<<dim3(4096, 2), 512, 0, stream>>>(fqkv, S);

    // 5. linear-attention K-side (output-split, direct to Mbuf) + Q-side
    kside2<<<dim3(4, 32), 256, 0, stream>>>(fqkv, rnkS, kvS, mkS, Mbuf);
    qside<<<dim3(16, 32), 256, 0, stream>>>(fqkv, Mbuf, rnqS, mqS, qvS, wmix, attnbf);

    // 6. q2 = q + attn @ Wout^T + bout  -> d_out
    mfma_gemm_nt<64, 64, 2, false><<<dim3(8, 64), 256, 0, stream>>>(
        attnbf, Woutbf, out, 4096, 512, 512, bout, q);

    // 7. MLP: x2 = LN(q2); h = gelu(x2@Wup^T+bup); out = q2 + h@Wdn^T + bdn
    lnsingle<<<1024, 256, 0, stream>>>(out, g2, b2n, x2bf);
    mfma_gemm_nt<64, 128, 3, true><<<dim3(16, 64), 256, 0, stream>>>(
        x2bf, Wupbf, hmid, 4096, 2048, 512, bup, nullptr);
    mfma_gemm_nt<64, 64, 2, false><<<dim3(8, 64), 256, 0, stream>>>(
        hmid, Wdnbf, out, 4096, 512, 2048, bdn, out);
}

// Round 9
// 277.442 us; speedup vs baseline: 1.0979x; 1.0979x over previous
//
#include <hip/hip_runtime.h>
#include <math.h>

#define EPS 1e-5f
#define ROWS 4096  // B*N

typedef __attribute__((ext_vector_type(8))) short short8;
typedef __attribute__((ext_vector_type(4))) short short4v;
typedef __attribute__((ext_vector_type(4))) float floatx4;

__device__ inline short f2bf(float f) {
    unsigned u = __builtin_bit_cast(unsigned, f);
    unsigned r = (u + 0x7fffu + ((u >> 16) & 1u)) >> 16;
    return (short)r;
}
__device__ inline float bf2f(short s) {
    unsigned u = ((unsigned)(unsigned short)s) << 16;
    return __builtin_bit_cast(float, u);
}

// ---------------------------------------------------------------------------
// prep: fused weight->bf16 conversion (blocks 0..1279), LN(q/k/v)->bf16
// (blocks 1280..4351), and zeroing of qgl/kgl (block 4352). 256 threads.
// ---------------------------------------------------------------------------
__global__ __launch_bounds__(256) void prep(
    const float* __restrict__ Win, const float* __restrict__ Wout,
    const float* __restrict__ Wup, const float* __restrict__ Wdn,
    short* __restrict__ Winbf, short* __restrict__ Woutbf,
    short* __restrict__ Wupbf, short* __restrict__ Wdnbf,
    const float* __restrict__ q, const float* __restrict__ k,
    const float* __restrict__ v, const float* __restrict__ g,
    const float* __restrict__ bb, short* __restrict__ qkvln,
    float* __restrict__ zbase) {
    int bid = blockIdx.x;
    int t = threadIdx.x;
    if (bid < 1280) {  // weight convert, 2048 elems per block
        int lb = bid;
        const float* src;
        short* dst;
        if (lb < 128) { src = Win; dst = Winbf; }
        else if (lb < 256) { lb -= 128; src = Wout; dst = Woutbf; }
        else if (lb < 768) { lb -= 256; src = Wup; dst = Wupbf; }
        else { lb -= 768; src = Wdn; dst = Wdnbf; }
        int idx = (lb * 256 + t) * 8;
        float4 v0 = *(const float4*)(src + idx);
        float4 v1 = *(const float4*)(src + idx + 4);
        short8 o;
        o[0] = f2bf(v0.x); o[1] = f2bf(v0.y); o[2] = f2bf(v0.z); o[3] = f2bf(v0.w);
        o[4] = f2bf(v1.x); o[5] = f2bf(v1.y); o[6] = f2bf(v1.z); o[7] = f2bf(v1.w);
        *(short8*)(dst + idx) = o;
    } else if (bid < 4352) {  // layernorm + bf16, 4 rows per block
        int lb = bid - 1280;
        int tensor = lb >> 10;
        const float* x = tensor == 0 ? q : (tensor == 1 ? k : v);
        int row = (lb & 1023) * 4 + (t >> 6);
        int col = (t & 63) * 8;
        const float* xr = x + (size_t)row * 512 + col;
        float4 v0 = *(const float4*)xr;
        float4 v1 = *(const float4*)(xr + 4);
        float s = v0.x + v0.y + v0.z + v0.w + v1.x + v1.y + v1.z + v1.w;
        float sq = v0.x * v0.x + v0.y * v0.y + v0.z * v0.z + v0.w * v0.w +
                   v1.x * v1.x + v1.y * v1.y + v1.z * v1.z + v1.w * v1.w;
#pragma unroll
        for (int off = 32; off; off >>= 1) {
            s += __shfl_xor(s, off);
            sq += __shfl_xor(sq, off);
        }
        float m = s * (1.f / 512.f);
        float rstd = rsqrtf(sq * (1.f / 512.f) - m * m + EPS);
        float4 g0 = *(const float4*)(g + col);
        float4 g1 = *(const float4*)(g + col + 4);
        float4 b0 = *(const float4*)(bb + col);
        float4 b1 = *(const float4*)(bb + col + 4);
        short8 o;
        o[0] = f2bf((v0.x - m) * rstd * g0.x + b0.x);
        o[1] = f2bf((v0.y - m) * rstd * g0.y + b0.y);
        o[2] = f2bf((v0.z - m) * rstd * g0.z + b0.z);
        o[3] = f2bf((v0.w - m) * rstd * g0.w + b0.w);
        o[4] = f2bf((v1.x - m) * rstd * g1.x + b1.x);
        o[5] = f2bf((v1.y - m) * rstd * g1.y + b1.y);
        o[6] = f2bf((v1.z - m) * rstd * g1.z + b1.z);
        o[7] = f2bf((v1.w - m) * rstd * g1.w + b1.w);
        *(short8*)(qkvln + (size_t)(tensor * 4096 + row) * 512 + col) = o;
    } else {  // zero qgl/kgl (1024 floats)
        float4 z = {0.f, 0.f, 0.f, 0.f};
        *(float4*)(zbase + t * 4) = z;
    }
}

// Single-tensor LN + bf16 (for x2 = LN(q2)). grid 1024 x 256 thr.
__global__ __launch_bounds__(256) void lnsingle(
    const float* __restrict__ x, const float* __restrict__ g,
    const float* __restrict__ bb, short* __restrict__ out) {
    int t = threadIdx.x;
    int row = blockIdx.x * 4 + (t >> 6);
    int col = (t & 63) * 8;
    const float* xr = x + (size_t)row * 512 + col;
    float4 v0 = *(const float4*)xr;
    float4 v1 = *(const float4*)(xr + 4);
    float s = v0.x + v0.y + v0.z + v0.w + v1.x + v1.y + v1.z + v1.w;
    float sq = v0.x * v0.x + v0.y * v0.y + v0.z * v0.z + v0.w * v0.w +
               v1.x * v1.x + v1.y * v1.y + v1.z * v1.z + v1.w * v1.w;
#pragma unroll
    for (int off = 32; off; off >>= 1) {
        s += __shfl_xor(s, off);
        sq += __shfl_xor(sq, off);
    }
    float m = s * (1.f / 512.f);
    float rstd = rsqrtf(sq * (1.f / 512.f) - m * m + EPS);
    float4 g0 = *(const float4*)(g + col);
    float4 g1 = *(const float4*)(g + col + 4);
    float4 b0 = *(const float4*)(bb + col);
    float4 b1 = *(const float4*)(bb + col + 4);
    short8 o;
    o[0] = f2bf((v0.x - m) * rstd * g0.x + b0.x);
    o[1] = f2bf((v0.y - m) * rstd * g0.y + b0.y);
    o[2] = f2bf((v0.z - m) * rstd * g0.z + b0.z);
    o[3] = f2bf((v0.w - m) * rstd * g0.w + b0.w);
    o[4] = f2bf((v1.x - m) * rstd * g1.x + b1.x);
    o[5] = f2bf((v1.y - m) * rstd * g1.y + b1.y);
    o[6] = f2bf((v1.z - m) * rstd * g1.z + b1.z);
    o[7] = f2bf((v1.w - m) * rstd * g1.w + b1.w);
    *(short8*)(out + (size_t)row * 512 + col) = o;
}

// ---------------------------------------------------------------------------
// bf16 MFMA NT GEMM, BK=64 (two 32-K sub-tiles per barrier pair).
// Tile TM x TN, 2x2 waves, 16x16x32 MFMA, global_load_lds width-16 staging.
// EPI: 0 plain, 2 +bias+resid, 3 gelu(x+bias).  OUT_BF16 selects C dtype.
// ---------------------------------------------------------------------------
template <int TM, int TN, int EPI, bool OUT_BF16>
__global__ __launch_bounds__(256) void mfma_gemm_nt(
    const short* __restrict__ A, const short* __restrict__ B,
    void* __restrict__ C, int M, int N, int K,
    const float* __restrict__ bias, const float* __restrict__ resid) {
    constexpr int FI = TM / 32;
    constexpr int FJ = TN / 32;
    __shared__ short As[2 * TM * 32];
    __shared__ short Bs[2 * TN * 32];
    int t = threadIdx.x;
    int m0 = blockIdx.y * TM, n0 = blockIdx.x * TN;
    int w = t >> 6, lane = t & 63;
    int wm = (w & 1) * (TM / 2), wn = (w >> 1) * (TN / 2);
    floatx4 acc[FI][FJ];
#pragma unroll
    for (int i = 0; i < FI; ++i)
#pragma unroll
        for (int j = 0; j < FJ; ++j) acc[i][j] = (floatx4){0.f, 0.f, 0.f, 0.f};

    int arow = t >> 2, acol = (t & 3) * 8;
    const short* Ag = A + (size_t)(m0 + arow) * K + acol;
    const short* Bg = B + (size_t)(n0 + arow) * K + acol;
    int ldsbase = w * 1024;  // bytes, wave-uniform

    for (int k0 = 0; k0 < K; k0 += 64) {
        __syncthreads();
#pragma unroll
        for (int u = 0; u < 2; ++u) {
#pragma unroll
            for (int r = 0; r < TM / 64; ++r)
                __builtin_amdgcn_global_load_lds(
                    (const __attribute__((address_space(1))) void*)(Ag + (size_t)r * 64 * K + k0 + 32 * u),
                    (__attribute__((address_space(3))) void*)((char*)As + u * TM * 64 + r * 4096 + ldsbase),
                    16, 0, 0);
#pragma unroll
            for (int r = 0; r < TN / 64; ++r)
                __builtin_amdgcn_global_load_lds(
                    (const __attribute__((address_space(1))) void*)(Bg + (size_t)r * 64 * K + k0 + 32 * u),
                    (__attribute__((address_space(3))) void*)((char*)Bs + u * TN * 64 + r * 4096 + ldsbase),
                    16, 0, 0);
        }
        __syncthreads();
        int krow = (lane >> 4) * 8;
#pragma unroll
        for (int u = 0; u < 2; ++u) {
            short8 af[FI], bf[FJ];
#pragma unroll
            for (int i = 0; i < FI; ++i)
                af[i] = *(const short8*)&As[u * TM * 32 + (wm + i * 16 + (lane & 15)) * 32 + krow];
#pragma unroll
            for (int j = 0; j < FJ; ++j)
                bf[j] = *(const short8*)&Bs[u * TN * 32 + (wn + j * 16 + (lane & 15)) * 32 + krow];
#pragma unroll
            for (int i = 0; i < FI; ++i)
#pragma unroll
                for (int j = 0; j < FJ; ++j)
                    acc[i][j] = __builtin_amdgcn_mfma_f32_16x16x32_bf16(
                        af[i], bf[j], acc[i][j], 0, 0, 0);
        }
    }

    int col = lane & 15, rbase = (lane >> 4) * 4;
#pragma unroll
    for (int i = 0; i < FI; ++i) {
#pragma unroll
        for (int j = 0; j < FJ; ++j) {
            int gcol = n0 + wn + j * 16 + col;
#pragma unroll
            for (int r = 0; r < 4; ++r) {
                int grow = m0 + wm + i * 16 + rbase + r;
                float v = acc[i][j][r];
                if (EPI == 2) v += bias[gcol] + resid[(size_t)grow * N + gcol];
                if (EPI == 3) {
                    v += bias[gcol];
                    v = 0.5f * v * (1.f + erff(v * 0.70710678118654752f));
                }
                if (OUT_BF16)
                    ((short*)C)[(size_t)grow * N + gcol] = f2bf(v);
                else
                    ((float*)C)[(size_t)grow * N + gcol] = v;
            }
        }
    }
}

// ---------------------------------------------------------------------------
// Per (head,row) stats from bf16 fqkv: mean, 1/norm, var(ddof=1).
// grid (4096, 2) y: fq/fk. 512 threads.
// ---------------------------------------------------------------------------
__global__ void head_stats2(const short* __restrict__ fqkv, float* __restrict__ S) {
    int row = blockIdx.x;
    int y = blockIdx.y;
    const short* f = fqkv + (size_t)y * 4096 * 512;
    float* base = S + (size_t)y * 98304;
    int t = threadIdx.x;
    int h = t >> 6, lane = t & 63;
    float v = bf2f(f[(size_t)row * 512 + t]);
    float s = v, sq = v * v;
#pragma unroll
    for (int off = 32; off; off >>= 1) {
        s += __shfl_xor(s, off);
        sq += __shfl_xor(sq, off);
    }
    if (lane == 0) {
        float m = s * (1.f / 64.f);
        int idx = h * ROWS + row;
        base[idx] = m;
        base[32768 + idx] = rsqrtf(sq);
        base[65536 + idx] = (sq - 64.f * m * m) * (1.f / 63.f);
    }
}

// Column means of LN(q)/LN(k) bf16 over 4096 rows. grid (128, 2), 512 thr.
__global__ void colmean_ln(const short* __restrict__ qkvln,
                           float* __restrict__ qgl, float* __restrict__ kgl) {
    int y = blockIdx.y;
    const short* f = qkvln + (size_t)y * 4096 * 512;
    float* o = y ? kgl : qgl;
    int col = threadIdx.x;
    int r0 = blockIdx.x * 32;
    float s = 0.f;
    for (int r = 0; r < 32; ++r) s += bf2f(f[(size_t)(r0 + r) * 512 + col]);
    atomicAdd(&o[col], s * (1.f / 4096.f));
}

// ---------------------------------------------------------------------------
// Fused: qg = qgl @ Win^T, kg = kgl @ Win^T (512-GEMV each), then per-head
// policy MLP -> wmix. One block, 512 threads.
// ---------------------------------------------------------------------------
__global__ __launch_bounds__(512) void policy_fused(
    const float* __restrict__ qgl, const float* __restrict__ kgl,
    const short* __restrict__ Winbf,
    const float* __restrict__ W1, const float* __restrict__ b1,
    const float* __restrict__ g, const float* __restrict__ bb,
    const float* __restrict__ W2, const float* __restrict__ b2,
    float* __restrict__ wmix) {
    __shared__ float qgl_s[512], kgl_s[512], qg_s[512], kg_s[512];
    int t = threadIdx.x;
    qgl_s[t] = qgl[t];
    kgl_s[t] = kgl[t];
    __syncthreads();
    const short* wr = Winbf + (size_t)t * 512;
    float accq = 0.f, acck = 0.f;
    for (int i = 0; i < 512; i += 8) {
        short8 w8 = *(const short8*)(wr + i);
#pragma unroll
        for (int u = 0; u < 8; ++u) {
            float wv = bf2f(w8[u]);
            accq += qgl_s[i + u] * wv;
            acck += kgl_s[i + u] * wv;
        }
    }
    qg_s[t] = accq;
    kg_s[t] = acck;
    __syncthreads();
    int h = t >> 6, j = t & 63;
    float acc = 0.f;
    const float* w1r = W1 + j * 128;
    for (int i = 0; i < 64; ++i) acc += qg_s[h * 64 + i] * w1r[i];
    for (int i = 0; i < 64; ++i) acc += kg_s[h * 64 + i] * w1r[64 + i];
    acc += b1[j];
    float s = acc, sq = acc * acc;
#pragma unroll
    for (int off = 32; off; off >>= 1) {
        s += __shfl_xor(s, off);
        sq += __shfl_xor(sq, off);
    }
    float m = s * (1.f / 64.f);
    float var = sq * (1.f / 64.f) - m * m;
    float xh = (acc - m) * rsqrtf(var + EPS) * g[j] + bb[j];
    float r = fmaxf(xh, 0.f);
    float l[3];
#pragma unroll
    for (int c = 0; c < 3; ++c) {
        float p = r * W2[c * 64 + j];
#pragma unroll
        for (int off = 32; off; off >>= 1) p += __shfl_xor(p, off);
        l[c] = p + b2[c];
    }
    if (j == 0) {
        float mx = fmaxf(l[0], fmaxf(l[1], l[2]));
        float e0 = expf(l[0] - mx), e1 = expf(l[1] - mx), e2 = expf(l[2] - mx);
        float inv = 1.f / (e0 + e1 + e2);
        wmix[h * 3 + 0] = e0 * inv;
        wmix[h * 3 + 1] = e1 * inv;
        wmix[h * 3 + 2] = e2 * inv;
    }
}

// ---------------------------------------------------------------------------
// K-side reduction, output-split + m-split: grid (4 dslice, 32 hb, 4 mchunk),
// 256 threads. Block computes rows d0..d0+15 of M1=(K*rnk)^T V and M2=K^T V
// over its 256 m-rows, storing a coalesced partial into Mpart[mc].
// ds==0 blocks also compute skv/smk partials. bf16 LDS staging (22 KB).
// ---------------------------------------------------------------------------
__global__ __launch_bounds__(256) void kside3(
    const short* __restrict__ fqkv,
    const float* __restrict__ rnk, const float* __restrict__ kvv,
    const float* __restrict__ mk, float* __restrict__ Mpart) {
    const short* fk = fqkv + (size_t)4096 * 512;
    const short* fv = fqkv + (size_t)2 * 4096 * 512;
    int ds = blockIdx.x, hb = blockIdx.y, mc = blockIdx.z;
    int h = hb >> 2, b = hb & 3;
    int d0 = ds * 16;
    __shared__ short fvt[128 * 64];  // 16 KB
    __shared__ short fkt[128 * 16];  // 4 KB
    __shared__ float rs[128], kvs[128], mks[128];
    int t = threadIdx.x;
    int d = t >> 4, e0 = (t & 15) * 4;
    float m1a[4] = {}, m2a[4] = {};
    float skv = 0.f, smk = 0.f;
    int mbase = mc * 256;
    for (int m0 = mbase; m0 < mbase + 256; m0 += 128) {
        __syncthreads();
        // stage fv tile (128 x 64) bf16
#pragma unroll
        for (int u = 0; u < 4; ++u) {
            int row = u * 32 + (t >> 3), col = (t & 7) * 8;
            short8 vs = *(const short8*)&fv[(size_t)(b * 1024 + m0 + row) * 512 + h * 64 + col];
            *(short8*)&fvt[row * 64 + col] = vs;
        }
        // stage fk tile (128 x 16) bf16, cols d0..d0+15
        {
            int row = t >> 1, col = (t & 1) * 8;
            short8 ksx = *(const short8*)&fk[(size_t)(b * 1024 + m0 + row) * 512 + h * 64 + d0 + col];
            *(short8*)&fkt[row * 16 + col] = ksx;
        }
        if (t < 128) {
            int sidx = h * ROWS + b * 1024 + m0 + t;
            rs[t] = rnk[sidx];
            kvs[t] = kvv[sidx];
            mks[t] = mk[sidx];
        }
        __syncthreads();
#pragma unroll 4
        for (int mi = 0; mi < 128; ++mi) {
            float kd = bf2f(fkt[mi * 16 + d]);
            float kr = kd * rs[mi];
            short4v vs = *(const short4v*)&fvt[mi * 64 + e0];
            float v0 = bf2f(vs[0]), v1 = bf2f(vs[1]), v2 = bf2f(vs[2]), v3 = bf2f(vs[3]);
            m2a[0] += kd * v0; m2a[1] += kd * v1; m2a[2] += kd * v2; m2a[3] += kd * v3;
            m1a[0] += kr * v0; m1a[1] += kr * v1; m1a[2] += kr * v2; m1a[3] += kr * v3;
        }
        if (ds == 0 && t < 64) {
#pragma unroll 4
            for (int mi = 0; mi < 128; ++mi) {
                float fvv = bf2f(fvt[mi * 64 + t]);
                skv += kvs[mi] * fvv;
                smk += mks[mi] * fvv;
            }
        }
    }
    float* base = Mpart + (size_t)(mc * 32 + hb) * 8320;
    *(float4*)&base[(d0 + d) * 64 + e0] = (float4){m1a[0], m1a[1], m1a[2], m1a[3]};
    *(float4*)&base[4096 + (d0 + d) * 64 + e0] = (float4){m2a[0], m2a[1], m2a[2], m2a[3]};
    if (ds == 0 && t < 64) {
        base[8192 + t] = skv;
        base[8256 + t] = smk;
    }
}

// ---------------------------------------------------------------------------
// Q-side apply, 64 rows per block. grid (16, 32). Sums the 4 kside partials
// while staging M1/M2 into LDS. Reads bf16 fq, writes bf16.
// ---------------------------------------------------------------------------
__global__ __launch_bounds__(256) void qside(
    const short* __restrict__ fqkv, const float* __restrict__ Mpart,
    const float* __restrict__ rnq, const float* __restrict__ mq,
    const float* __restrict__ qv, const float* __restrict__ wmix,
    short* __restrict__ attn_out) {
    const short* fq = fqkv;
    int ntile = blockIdx.x, hb = blockIdx.y;
    int h = hb >> 2, b = hb & 3;
    __shared__ float M1s[4096], M2s[4096], fqt[4096];
    __shared__ float Skvs[64], Smks[64], rnqs[64], mqs[64], qvs[64];
    int t = threadIdx.x;
    const float* c0 = Mpart + (size_t)hb * 8320;
    const float* c1 = c0 + (size_t)32 * 8320;
    const float* c2p = c1 + (size_t)32 * 8320;
    const float* c3p = c2p + (size_t)32 * 8320;
#pragma unroll
    for (int u = 0; u < 4; ++u) {
        int idx = t * 4 + u * 1024;
        float4 a0 = *(const float4*)&c0[idx];
        float4 a1 = *(const float4*)&c1[idx];
        float4 a2 = *(const float4*)&c2p[idx];
        float4 a3 = *(const float4*)&c3p[idx];
        *(float4*)&M1s[idx] = (float4){a0.x + a1.x + a2.x + a3.x, a0.y + a1.y + a2.y + a3.y,
                                       a0.z + a1.z + a2.z + a3.z, a0.w + a1.w + a2.w + a3.w};
        float4 b0 = *(const float4*)&c0[4096 + idx];
        float4 b1 = *(const float4*)&c1[4096 + idx];
        float4 b2 = *(const float4*)&c2p[4096 + idx];
        float4 b3 = *(const float4*)&c3p[4096 + idx];
        *(float4*)&M2s[idx] = (float4){b0.x + b1.x + b2.x + b3.x, b0.y + b1.y + b2.y + b3.y,
                                       b0.z + b1.z + b2.z + b3.z, b0.w + b1.w + b2.w + b3.w};
    }
    int n0 = ntile * 64;
#pragma unroll
    for (int u = 0; u < 2; ++u) {
        int idx = u * 2048 + t * 8;
        int r = idx >> 6, d = idx & 63;
        short8 qs = *(const short8*)&fq[(size_t)(b * 1024 + n0 + r) * 512 + h * 64 + d];
#pragma unroll
        for (int uu = 0; uu < 8; ++uu) fqt[idx + uu] = bf2f(qs[uu]);
    }
    if (t < 64) {
        Skvs[t] = c0[8192 + t] + c1[8192 + t] + c2p[8192 + t] + c3p[8192 + t];
        Smks[t] = c0[8256 + t] + c1[8256 + t] + c2p[8256 + t] + c3p[8256 + t];
        int sidx = h * ROWS + b * 1024 + n0 + t;
        rnqs[t] = rnq[sidx];
        mqs[t] = mq[sidx];
        qvs[t] = qv[sidx];
    }
    __syncthreads();
    float cw = wmix[h * 3 + 0], covw = wmix[h * 3 + 1], vw = wmix[h * 3 + 2];
    int e = t & 63, rq = t >> 6;
    float a1[16] = {}, a2[16] = {};
    for (int d4 = 0; d4 < 64; d4 += 4) {
        float md1[4], md2[4];
#pragma unroll
        for (int dd = 0; dd < 4; ++dd) {
            md1[dd] = M1s[(d4 + dd) * 64 + e];
            md2[dd] = M2s[(d4 + dd) * 64 + e];
        }
#pragma unroll
        for (int i = 0; i < 16; ++i) {
            float4 f = *(const float4*)&fqt[(rq * 16 + i) * 64 + d4];
            a1[i] += f.x * md1[0] + f.y * md1[1] + f.z * md1[2] + f.w * md1[3];
            a2[i] += f.x * md2[0] + f.y * md2[1] + f.z * md2[2] + f.w * md2[3];
        }
    }
    float c2c = covw * (1.f / 64.f), c3c = vw * (1.f / 64.f);
#pragma unroll
    for (int i = 0; i < 16; ++i) {
        int rr = rq * 16 + i;
        float v = cw * rnqs[rr] * a1[i] + c2c * a2[i] + c3c * qvs[rr] * Skvs[e] -
                  covw * mqs[rr] * Smks[e];
        attn_out[(size_t)(b * 1024 + n0 + rr) * 512 + h * 64 + e] = f2bf(v);
    }
}

// ---------------------------------------------------------------------------
extern "C" void kernel_launch(void* const* d_in, const int* in_sizes, int n_in,
                              void* d_out, int out_size, void* d_ws, size_t ws_size,
                              hipStream_t stream) {
    const float* q = (const float*)d_in[0];
    const float* k = (const float*)d_in[1];
    const float* v = (const float*)d_in[2];
    const float* Win = (const float*)d_in[3];
    const float* Wout = (const float*)d_in[4];
    const float* bout = (const float*)d_in[5];
    const float* g1 = (const float*)d_in[6];
    const float* b1n = (const float*)d_in[7];
    const float* g2 = (const float*)d_in[8];
    const float* b2n = (const float*)d_in[9];
    const float* Wup = (const float*)d_in[10];
    const float* bup = (const float*)d_in[11];
    const float* Wdn = (const float*)d_in[12];
    const float* bdn = (const float*)d_in[13];
    const float* wpW1 = (const float*)d_in[14];
    const float* wpb1 = (const float*)d_in[15];
    const float* wpg = (const float*)d_in[16];
    const float* wpb = (const float*)d_in[17];
    const float* wpW2 = (const float*)d_in[18];
    const float* wpb2 = (const float*)d_in[19];
    float* out = (float*)d_out;

    float* wsf = (float*)d_ws;
    short* fqkv = (short*)wsf;                   // 12288x512 bf16
    short* qkvln = (short*)(wsf + 4000000);      // 12288x512 bf16
    short* attnbf = (short*)(wsf + 8000000);     // 4096x512 bf16
    short* x2bf = (short*)(wsf + 10000000);      // 4096x512 bf16
    short* hmid = (short*)(wsf + 12000000);      // 4096x2048 bf16
    short* Winbf = (short*)(wsf + 17000000);
    short* Woutbf = Winbf + 262144;
    short* Wupbf = Woutbf + 262144;
    short* Wdnbf = Wupbf + 1048576;
    float* S = wsf + 19000000;                   // [2][3][32768]
    float* qgl = S + 196608;                     // 512
    float* kgl = qgl + 512;                      // 512
    float* wmix = kgl + 512;                     // 32
    float* Mpart = wsf + 19400000;               // 4*32*8320
    float* mqS = S, *rnqS = S + 32768, *qvS = S + 65536;
    float* mkS = S + 98304, *rnkS = S + 131072, *kvS = S + 163840;

    // 1. prep: weights->bf16, LN(q/k/v)->bf16, zero qgl/kgl
    prep<<<4353, 256, 0, stream>>>(Win, Wout, Wup, Wdn, Winbf, Woutbf, Wupbf,
                                   Wdnbf, q, k, v, g1, b1n, qkvln, qgl);

    // 2. stacked projection: fqkv = LN(qkv) @ Win^T  (M=12288), bf16 out
    mfma_gemm_nt<64, 128, 0, true><<<dim3(4, 192), 256, 0, stream>>>(
        qkvln, Winbf, fqkv, 12288, 512, 512, nullptr, nullptr);

    // 3. policy path: colmean of LN(q)/LN(k) -> GEMV + MLP -> wmix
    colmean_ln<<<dim3(128, 2), 512, 0, stream>>>(qkvln, qgl, kgl);
    policy_fused<<<1, 512, 0, stream>>>(qgl, kgl, Winbf, wpW1, wpb1, wpg, wpb,
                                        wpW2, wpb2, wmix);

    // 4. per-(head,row) stats
    head_stats2<<<dim3(4096, 2), 512, 0, stream>>>(fqkv, S);

    // 5. linear-attention K-side (output+m split, 512 blocks) + Q-side
    kside3<<<dim3(4, 32, 4), 256, 0, stream>>>(fqkv, rnkS, kvS, mkS, Mpart);
    qside<<<dim3(16, 32), 256, 0, stream>>>(fqkv, Mpart, rnqS, mqS, qvS, wmix, attnbf);

    // 6. q2 = q + attn @ Wout^T + bout  -> d_out
    mfma_gemm_nt<64, 64, 2, false><<<dim3(8, 64), 256, 0, stream>>>(
        attnbf, Woutbf, out, 4096, 512, 512, bout, q);

    // 7. MLP: x2 = LN(q2); h = gelu(x2@Wup^T+bup); out = q2 + h@Wdn^T + bdn
    lnsingle<<<1024, 256, 0, stream>>>(out, g2, b2n, x2bf);
    mfma_gemm_nt<64, 128, 3, true><<<dim3(16, 64), 256, 0, stream>>>(
        x2bf, Wupbf, hmid, 4096, 2048, 512, bup, nullptr);
    mfma_gemm_nt<64, 64, 2, false><<<dim3(8, 64), 256, 0, stream>>>(
        hmid, Wdnbf, out, 4096, 512, 2048, bdn, out);
}